// Round 10
// baseline (448.286 us; speedup 1.0000x reference)
//
#include <hip/hip_runtime.h>
#include <math.h>

#define AUX_SLOTS 1024
#define CAP 24576   // per-router ent segment capacity (expected count ~16384, sigma ~150)

// ---------------- vl: normalized V-projections, layout [R][H][L] ----------------
__global__ __launch_bounds__(256) void vl_kernel(const float* __restrict__ llm,
                                                 const float* __restrict__ Vw,
                                                 const float* __restrict__ Vb,
                                                 float* __restrict__ vl) {
    int b = blockIdx.x;          // b = r*64 + l
    int r = b >> 6, l = b & 63;
    int tid = threadIdx.x;
    int t = tid & 63, q = tid >> 6;    // t = h, q = K-quarter
    const float* w  = Vw + ((size_t)r * 384 + q * 96) * 64 + t;
    const float* xr = llm + l * 384 + q * 96;
    float acc = 0.f;
#pragma unroll 4
    for (int d = 0; d < 96; ++d) acc += xr[d] * w[(size_t)d * 64];
    __shared__ float red[256];
    red[tid] = acc;
    __syncthreads();
    if (q == 0) {
        acc = red[t] + red[64 + t] + red[128 + t] + red[192 + t] + Vb[r * 64 + t];
        float ss = acc * acc;
#pragma unroll
        for (int m = 1; m < 64; m <<= 1) ss += __shfl_xor(ss, m);
        float inv = 1.0f / fmaxf(sqrtf(ss), 1e-12f);
        vl[((size_t)r * 64 + t) * 64 + l] = acc * inv;   // [r][h][l]
    }
}

// ---------------- gate: logits, top-2, aux partials, DIRECT scatter ----------------
__global__ __launch_bounds__(256) void gate_kernel(
    const float* __restrict__ eh, const float* __restrict__ sr,
    const float* __restrict__ gw, const float* __restrict__ gb,
    int* __restrict__ ent, float* __restrict__ ewt,
    float* __restrict__ aux, int* __restrict__ cnt, int N)
{
    __shared__ int lcnt[8], lbase[8], lcur[8];
    __shared__ int   s_r01[32];
    __shared__ float s_w0[32], s_w1[32];
    int tid = threadIdx.x;
    if (tid < 8) { lcnt[tid] = 0; lcur[tid] = 0; }
    __syncthreads();
    int wave = tid >> 6, lane = tid & 63;
    int wgid = blockIdx.x * 4 + wave;
    float gbr[8];
#pragma unroll
    for (int r = 0; r < 8; ++r) gbr[r] = gb[r];
    float aux_acc = 0.f;

    for (int rr = 0; rr < 8; ++rr) {
        int row = wgid * 8 + rr;
        const float4* pa = (const float4*)(eh + (size_t)row * 384);
        const float4* pb = (const float4*)(sr + (size_t)row * 384);
        float4 xv0 = pa[lane];
        const float4* p1 = (lane < 32) ? (pa + 64 + lane) : (pb + (lane - 32));
        float4 xv1 = *p1;
        float4 xv2 = pb[lane + 32];

        float lg[8];
#pragma unroll
        for (int r = 0; r < 8; ++r) lg[r] = 0.f;
        {
            const float* g0 = gw + (size_t)lane * 32;
            const float* g1 = gw + (size_t)(lane + 64) * 32;
            const float* g2 = gw + (size_t)(lane + 128) * 32;
            float xd;
#pragma unroll
            for (int dd = 0; dd < 4; ++dd) {
                xd = (dd == 0) ? xv0.x : (dd == 1) ? xv0.y : (dd == 2) ? xv0.z : xv0.w;
#pragma unroll
                for (int r = 0; r < 8; ++r) lg[r] += xd * g0[dd * 8 + r];
            }
#pragma unroll
            for (int dd = 0; dd < 4; ++dd) {
                xd = (dd == 0) ? xv1.x : (dd == 1) ? xv1.y : (dd == 2) ? xv1.z : xv1.w;
#pragma unroll
                for (int r = 0; r < 8; ++r) lg[r] += xd * g1[dd * 8 + r];
            }
#pragma unroll
            for (int dd = 0; dd < 4; ++dd) {
                xd = (dd == 0) ? xv2.x : (dd == 1) ? xv2.y : (dd == 2) ? xv2.z : xv2.w;
#pragma unroll
                for (int r = 0; r < 8; ++r) lg[r] += xd * g2[dd * 8 + r];
            }
        }
#pragma unroll
        for (int m = 1; m < 64; m <<= 1) {
#pragma unroll
            for (int r = 0; r < 8; ++r) lg[r] += __shfl_xor(lg[r], m);
        }
#pragma unroll
        for (int r = 0; r < 8; ++r) lg[r] += gbr[r];

        float mx = lg[0];
#pragma unroll
        for (int r = 1; r < 8; ++r) mx = fmaxf(mx, lg[r]);
        float e8[8], se = 0.f;
#pragma unroll
        for (int r = 0; r < 8; ++r) { e8[r] = expf(lg[r] - mx); se += e8[r]; }

        int r0 = 0; float v0 = lg[0];
#pragma unroll
        for (int r = 1; r < 8; ++r) if (lg[r] > v0) { v0 = lg[r]; r0 = r; }
        int r1 = (r0 == 0) ? 1 : 0; float v1 = lg[r1];
#pragma unroll
        for (int r = 0; r < 8; ++r) if (r != r1 && r != r0 && lg[r] > v1) { v1 = lg[r]; r1 = r; }
        float z = expf(v1 - v0);
        float w0 = 1.f / (1.f + z), w1 = z / (1.f + z);

        if (lane == 0) {
            s_r01[wave * 8 + rr] = r0 | (r1 << 4);
            s_w0[wave * 8 + rr] = w0;
            s_w1[wave * 8 + rr] = w1;
            atomicAdd(&lcnt[r0], 1);
            atomicAdd(&lcnt[r1], 1);
        }
#pragma unroll
        for (int r2 = 0; r2 < 8; ++r2) {
            if (lane == r2) aux_acc += e8[r2] / se;
            if (lane - 8 == r2) aux_acc += (r2 == r0 || r2 == r1) ? 1.f : 0.f;
        }
    }
    if (lane < 16) atomicAdd(aux + ((size_t)(wgid & (AUX_SLOTS - 1)) * 16) + lane, aux_acc);
    __syncthreads();
    if (tid < 8) lbase[tid] = atomicAdd(&cnt[tid], lcnt[tid]);
    __syncthreads();
    if (tid < 32) {   // one thread per row of this block: write both entries
        int ri = s_r01[tid];
        int row = blockIdx.x * 32 + tid;
        int r0 = ri & 15, r1 = (ri >> 4) & 15;
        int p0 = lbase[r0] + atomicAdd(&lcur[r0], 1);
        ent[r0 * CAP + p0] = row << 1;       ewt[r0 * CAP + p0] = s_w0[tid];
        int p1 = lbase[r1] + atomicAdd(&lcur[r1], 1);
        ent[r1 * CAP + p1] = (row << 1) | 1; ewt[r1 * CAP + p1] = s_w1[tid];
    }
}

// ---------------- fused projection GEMM + l2norm + scores + softmax ----------------
// ROUND-10: single-wave blocks. r2's loop byte-for-byte (4x8 micro-tile,
// K-chunk 32, same swizzle), but each block = ONE wave owning a 32-row tile
// with private x-slice (4KB) + private U copy (8KB). Rationale: in r2, each
// wave only ever reads its own 32 xs rows; the only shared data was U. With
// 1-wave blocks, __syncthreads degenerates to the wave's own inherent
// vmcnt/lgkm waits (no cross-wave drain coupling), and ~13 co-resident
// blocks/CU (12.5KB LDS each) drift out of phase, covering each other's
// staging latency. Cost: 4x U L2 re-reads (~786MB L2 ~= 23us, absorbed).
// vl no longer fits LDS -> scores phase reads it from global (16KB/router,
// L1-resident, 8-lane broadcast per address). Epilogue otherwise unchanged.
__global__ __launch_bounds__(64, 1) void gemm_kernel(
    const float* __restrict__ eh, const float* __restrict__ sr,
    const float* __restrict__ Uw, const float* __restrict__ Ub,
    const float* __restrict__ vl, const int* __restrict__ ent,
    const float* __restrict__ ewt, const int* __restrict__ cnt,
    float* __restrict__ probs)
{
    int r = blockIdx.y;
    int count = cnt[r]; if (count > CAP) count = CAP;
    int tile = blockIdx.x;
    if (tile * 32 >= count) return;
    int base = r * CAP + tile * 32;

    __shared__ float xs[32 * 32];    // 4 KB, f4-swizzled [row][k4 ^ ((row>>2)&7)]
    __shared__ float us[32 * 64];    // 8 KB, private U chunk [k][h]
    __shared__ int   sent[32];
    __shared__ float swt[32];

    int tid = threadIdx.x;           // 0..63, one wave
    int tx = tid & 7, ty = tid >> 3; // ty 0..7, rows 4ty..4ty+3; h 8tx..8tx+7
    float4* xs4 = (float4*)xs;
    float4* us4 = (float4*)us;

    if (tid < 32) {
        bool act = (tile * 32 + tid) < count;
        sent[tid] = act ? ent[base + tid] : -1;
        swt[tid]  = act ? ewt[base + tid] : 0.f;
    }
    __syncthreads();   // 1-wave: just the wave's own lgkm wait

    // staging row ids (rloc = ty + 8p)
    int rowp[4];
#pragma unroll
    for (int p = 0; p < 4; ++p) {
        int e = sent[ty + 8 * p];
        rowp[p] = (e < 0) ? 0 : (e >> 1);
    }

    float acc[4][8];
#pragma unroll
    for (int i = 0; i < 4; ++i)
#pragma unroll
        for (int j = 0; j < 8; ++j) acc[i][j] = 0.f;

    for (int c = 0; c < 24; ++c) {
        const float* xsrc = (c < 12) ? eh : sr;
        int dd0 = ((c < 12) ? c : c - 12) * 32;
        {   // stage x slice: 4 f4 per lane
#pragma unroll
            for (int p = 0; p < 4; ++p) {
                int rloc = ty + 8 * p;
                float4 v = ((const float4*)(xsrc + (size_t)rowp[p] * 384 + dd0))[tx];
                xs4[rloc * 8 + (tx ^ ((rloc >> 2) & 7))] = v;
            }
        }
        {   // stage private U chunk [32k][64h]: 8 f4 per lane
            const float4* pu = (const float4*)(Uw + ((size_t)r * 768 + (size_t)c * 32) * 64);
#pragma unroll
            for (int p = 0; p < 8; ++p) us4[tid + p * 64] = pu[tid + p * 64];
        }
        __syncthreads();
#pragma unroll
        for (int k4 = 0; k4 < 8; ++k4) {
            float4 a[4];
#pragma unroll
            for (int i = 0; i < 4; ++i)
                a[i] = xs4[(4 * ty + i) * 8 + (k4 ^ (ty & 7))];
#pragma unroll
            for (int j = 0; j < 4; ++j) {
                float4 b0 = us4[(k4 * 4 + j) * 16 + tx * 2];
                float4 b1 = us4[(k4 * 4 + j) * 16 + tx * 2 + 1];
#pragma unroll
                for (int i = 0; i < 4; ++i) {
                    float av = (j == 0) ? a[i].x : (j == 1) ? a[i].y : (j == 2) ? a[i].z : a[i].w;
                    acc[i][0] += av * b0.x; acc[i][1] += av * b0.y;
                    acc[i][2] += av * b0.z; acc[i][3] += av * b0.w;
                    acc[i][4] += av * b1.x; acc[i][5] += av * b1.y;
                    acc[i][6] += av * b1.z; acc[i][7] += av * b1.w;
                }
            }
        }
        __syncthreads();
    }

    // bias + l2-normalize rows (partial over tx, xor-shfl 1,2,4)
    float ub[8];
#pragma unroll
    for (int j = 0; j < 8; ++j) ub[j] = Ub[r * 64 + 8 * tx + j];
#pragma unroll
    for (int i = 0; i < 4; ++i) {
        float ss = 0.f;
#pragma unroll
        for (int j = 0; j < 8; ++j) { acc[i][j] += ub[j]; ss += acc[i][j] * acc[i][j]; }
#pragma unroll
        for (int m = 1; m <= 4; m <<= 1) ss += __shfl_xor(ss, m);
        float inv = 1.0f / fmaxf(sqrtf(ss), 1e-12f);
#pragma unroll
        for (int j = 0; j < 8; ++j) acc[i][j] *= inv;
    }

    // scores + softmax + store; vl read directly from global (L1-resident)
    const float4* pv = (const float4*)(vl + (size_t)r * 4096);
#pragma unroll
    for (int ih = 0; ih < 4; ih += 2) {
        float sc[2][8];
        for (int lc = 0; lc < 8; ++lc) {
            float part[2][8];
#pragma unroll
            for (int i = 0; i < 2; ++i)
#pragma unroll
                for (int j = 0; j < 8; ++j) part[i][j] = 0.f;
#pragma unroll
            for (int j = 0; j < 8; ++j) {
                int h = 8 * tx + j;
                float4 v0 = pv[h * 16 + 2 * lc];
                float4 v1 = pv[h * 16 + 2 * lc + 1];
#pragma unroll
                for (int i = 0; i < 2; ++i) {
                    float uv = acc[ih + i][j];
                    part[i][0] += uv * v0.x; part[i][1] += uv * v0.y;
                    part[i][2] += uv * v0.z; part[i][3] += uv * v0.w;
                    part[i][4] += uv * v1.x; part[i][5] += uv * v1.y;
                    part[i][6] += uv * v1.z; part[i][7] += uv * v1.w;
                }
            }
#pragma unroll
            for (int m = 1; m <= 4; m <<= 1)
#pragma unroll
                for (int i = 0; i < 2; ++i)
#pragma unroll
                    for (int j = 0; j < 8; ++j) part[i][j] += __shfl_xor(part[i][j], m);
            if (tx == lc) {
#pragma unroll
                for (int i = 0; i < 2; ++i)
#pragma unroll
                    for (int j = 0; j < 8; ++j) sc[i][j] = part[i][j];
            }
        }
#pragma unroll
        for (int i = 0; i < 2; ++i) {
            float mx = sc[i][0];
#pragma unroll
            for (int j = 1; j < 8; ++j) mx = fmaxf(mx, sc[i][j]);
#pragma unroll
            for (int m = 1; m <= 4; m <<= 1) mx = fmaxf(mx, __shfl_xor(mx, m));
            float e[8], ssum = 0.f;
#pragma unroll
            for (int j = 0; j < 8; ++j) { e[j] = expf(sc[i][j] - mx); ssum += e[j]; }
#pragma unroll
            for (int m = 1; m <= 4; m <<= 1) ssum += __shfl_xor(ssum, m);
            int rloc = 4 * ty + ih + i;
            int ei = sent[rloc];
            if (ei >= 0) {
                float w = swt[rloc];
                float4 o0, o1;
                o0.x = (e[0] / ssum) * w; o0.y = (e[1] / ssum) * w;
                o0.z = (e[2] / ssum) * w; o0.w = (e[3] / ssum) * w;
                o1.x = (e[4] / ssum) * w; o1.y = (e[5] / ssum) * w;
                o1.z = (e[6] / ssum) * w; o1.w = (e[7] / ssum) * w;
                size_t bo = (size_t)(ei >> 1) * 128 + (size_t)(ei & 1) * 64 + 8 * tx;
                *(float4*)(probs + bo) = o0;
                *(float4*)(probs + bo + 4) = o1;
            }
        }
    }
}

// ---------------- combine: p = k0+k1, sequential cumsum, select, log ----------------
__global__ __launch_bounds__(256) void combine_kernel(
    const float* __restrict__ probs, const float* __restrict__ rnd,
    float* __restrict__ out, int N)
{
    int w = threadIdx.x >> 6, lane = threadIdx.x & 63;
    int n = blockIdx.x * 4 + w;
    float p = probs[(size_t)n * 128 + lane] + probs[(size_t)n * 128 + 64 + lane];
    float rn = rnd[n];
    float c = 0.f; int sel = 0; bool found = false;
    for (int l = 0; l < 64; ++l) {
        float v = __shfl(p, l);
        c += v;
        if (!found && c > rn) { sel = l; found = true; }
    }
    float pv = __shfl(p, sel);
    if (lane == 0) {
        out[n] = (float)sel;
        out[N + n] = logf(pv);
    }
}

__global__ __launch_bounds__(256) void aux_kernel(const float* __restrict__ aux,
                                                  float* __restrict__ out, int N) {
    __shared__ float red[256];
    int tid = threadIdx.x;
    int j = tid & 15, s0 = tid >> 4;
    float acc = 0.f;
    for (int s = s0; s < AUX_SLOTS; s += 16) acc += aux[s * 16 + j];
    red[tid] = acc;
    __syncthreads();
    if (tid < 16) {
        float a = 0.f;
        for (int g = 0; g < 16; ++g) a += red[g * 16 + tid];
        red[tid] = a;
    }
    __syncthreads();
    if (tid == 0) {
        float invN = 1.f / (float)N;
        float t = 0.f;
        for (int r2 = 0; r2 < 8; ++r2) t += (red[r2] * invN) * (red[8 + r2] * invN);
        out[2 * N] = 8.0f * 0.05f * t;
    }
}

extern "C" void kernel_launch(void* const* d_in, const int* in_sizes, int n_in,
                              void* d_out, int out_size, void* d_ws, size_t ws_size,
                              hipStream_t stream) {
    const float* eh  = (const float*)d_in[0];
    const float* sr  = (const float*)d_in[1];
    const float* llm = (const float*)d_in[2];
    const float* rnd = (const float*)d_in[3];
    const float* gw  = (const float*)d_in[4];
    const float* gb  = (const float*)d_in[5];
    const float* Uw  = (const float*)d_in[6];
    const float* Ub  = (const float*)d_in[7];
    const float* Vw  = (const float*)d_in[8];
    const float* Vb  = (const float*)d_in[9];
    int N = in_sizes[0] / 384;

    float* vl    = (float*)d_ws;              // 32768 f
    float* aux   = vl + 32768;                // 16384 f
    int*   cnt   = (int*)(aux + 16384);       // 8 i
    int*   ent   = cnt + 8;                   // 8*CAP i
    float* ewt   = (float*)(ent + 8 * CAP);   // 8*CAP f
    float* probs = ewt + 8 * CAP;             // N*128 f

    hipMemsetAsync(aux, 0, 16384 * sizeof(float) + 8 * sizeof(int), stream);
    vl_kernel<<<512, 256, 0, stream>>>(llm, Vw, Vb, vl);
    gate_kernel<<<N / 32, 256, 0, stream>>>(eh, sr, gw, gb, ent, ewt, aux, cnt, N);
    gemm_kernel<<<dim3(CAP / 32, 8), 64, 0, stream>>>(eh, sr, Uw, Ub, vl, ent, ewt,
                                                      cnt, probs);
    combine_kernel<<<N / 4, 256, 0, stream>>>(probs, rnd, (float*)d_out, N);
    aux_kernel<<<1, 256, 0, stream>>>(aux, (float*)d_out, N);
}